// Round 8
// baseline (340.307 us; speedup 1.0000x reference)
//
#include <hip/hip_runtime.h>

// NeurTWs R18 = R17 body (55.7us steady, 84 VGPR, no spill, fA01-deep
// prefetch) + wave-level work-stealing. R17 post-mortem: prediction
// matched (59->55.7, FETCH back to 131.7MB). Traffic model now locked:
// compulsory ~41MB; the ~100MB excess = 8 XCDs x 12.8MB feat16 -- every
// XCD's private 4MB L2 streams the whole table, L3 serves the misses
// (pos16 null in R16 proves pos isn't the term). Binning costed out:
// inverse-permutation on out costs ~30-60MB allocate traffic + 2 kernels
// = net zero. fp8 feat: absmax est 0.02-0.03, too risky. => feat traffic
// irreducible; remaining slack is SCHEDULING: 4096 block-tiles / 768
// blocks = 5.33 -> blocks 0-255 run a 6th iter while 2/3 of the machine
// idles (occ 28% < 37.5% theoretical confirms). R18: decompose into
// 16384 x 64-row WAVE-tiles pulled from a global atomic cursor. Waves
// are already independent (hpe slices wave-private, wm1t read-only, no
// in-loop barriers). Lane0 atomicAdd + shfl broadcast; steal for tile
// i+1 issued at iter-i top so the R17 prefetch pipeline is intact.
// Counter at ws[0] (feat16 moved to +256), zeroed via hipMemsetAsync
// (graph-capture legal); static-stride fallback if ws < 4B.
// Predicted: 55.7 -> 49-52.5us, occ ~34%, FETCH ~132MB, WRITE ~11MB.
// Pre-commit: >=54us => tail was free => pivot to global_load_lds feat
// ring (MLP depth) or declare near-roofline on the L2-miss path.
// Fragment layouts (gfx950, verified): A/B: idx=lane&15, k=(lane>>4)*8+j;
// C/D: col=lane&15, row=(lane>>4)*4+reg.

typedef _Float16 half8 __attribute__((ext_vector_type(8)));
typedef float floatx4 __attribute__((ext_vector_type(4)));

#define HSTR 40    // h/pe row stride (f16): 80 B
#define WSTR 104   // wm1t row stride (f16): 208 B
#define GRID_MAIN 768

__global__ void feat_to_f16(const float* __restrict__ nf,
                            _Float16* __restrict__ o, int n8) {
    int t = blockIdx.x * 256 + threadIdx.x;
    if (t >= n8) return;
    const float4* p = (const float4*)nf + (size_t)t * 2;
    const float4 a = p[0], b = p[1];
    half8 h;
    h[0] = (_Float16)a.x; h[1] = (_Float16)a.y;
    h[2] = (_Float16)a.z; h[3] = (_Float16)a.w;
    h[4] = (_Float16)b.x; h[5] = (_Float16)b.y;
    h[6] = (_Float16)b.z; h[7] = (_Float16)b.w;
    *((half8*)o + t) = h;
}

// load feat A-fragments for 2 row-tiles (nd0 -> fA[0], nd1 -> fA[1])
__device__ __forceinline__ void load_feat2(const _Float16* __restrict__ feat16,
                                           const float* __restrict__ node_feat,
                                           int use_f16, int nd0, int nd1, int q,
                                           half8 fA[2][2]) {
    if (use_f16) {
        const _Float16* fb0 = feat16 + (size_t)nd0 * 64 + q * 8;
        const _Float16* fb1 = feat16 + (size_t)nd1 * 64 + q * 8;
        fA[0][0] = *(const half8*)(fb0);
        fA[0][1] = *(const half8*)(fb0 + 32);
        fA[1][0] = *(const half8*)(fb1);
        fA[1][1] = *(const half8*)(fb1 + 32);
    } else {
        #pragma unroll
        for (int rr = 0; rr < 2; ++rr) {
            const float* fb = node_feat + (size_t)(rr ? nd1 : nd0) * 64 + q * 8;
            #pragma unroll
            for (int kt = 0; kt < 2; ++kt) {
                const float4 lo = *(const float4*)(fb + kt * 32);
                const float4 hi = *(const float4*)(fb + kt * 32 + 4);
                half8 h;
                h[0] = (_Float16)lo.x; h[1] = (_Float16)lo.y;
                h[2] = (_Float16)lo.z; h[3] = (_Float16)lo.w;
                h[4] = (_Float16)hi.x; h[5] = (_Float16)hi.y;
                h[6] = (_Float16)hi.z; h[7] = (_Float16)hi.w;
                fA[rr][kt] = h;
            }
        }
    }
}

__global__ __launch_bounds__(256, 3) void neurtw_r18(
    const float* __restrict__ pos_table,   // [NUM_KEYS, 4]
    const float* __restrict__ node_feat,   // [NUM_NODES, 64] fp32 (fallback)
    const float* __restrict__ W1,          // [4, 32]
    const float* __restrict__ b1,          // [32]
    const float* __restrict__ W2,          // [32, 32]
    const float* __restrict__ b2,          // [32]
    const float* __restrict__ Wm1,         // [96, 64]
    const float* __restrict__ bm1,         // [64]
    const float* __restrict__ Wm2,         // [64, 1]
    const float* __restrict__ bm2,         // [1]
    const int*   __restrict__ key_idx,     // [rows]
    const int*   __restrict__ node_idx,    // [rows]
    const _Float16* __restrict__ feat16,   // [NUM_NODES, 64] f16 (ws)
    int use_f16,
    int*         __restrict__ cursor,      // [1] (ws) tile cursor
    int use_steal,
    float*       __restrict__ out,         // [rows]
    int rows)
{
    __shared__ _Float16 hpe[256 * HSTR];   // 20 KB (h then pe; wave-private)
    __shared__ _Float16 wm1t[64 * WSTR];   // 13 KB  wm1t[n][k] = Wm1[k][n]

    const int tid  = threadIdx.x;
    const int lane = tid & 63;
    const int r0   = (tid >> 6) * 64;
    const int ln   = lane & 15;
    const int q    = lane >> 4;

    // ---------- once per block: stage Wm1^T into LDS ----------
    #pragma unroll
    for (int i = 0; i < 3; ++i) {
        const int task = i * 256 + tid;
        const int n = task & 63, k8 = task >> 6;
        half8 w;
        #pragma unroll
        for (int kk = 0; kk < 8; ++kk)
            w[kk] = (_Float16)Wm1[(k8 * 8 + kk) * 64 + n];
        *(half8*)(&wm1t[n * WSTR + k8 * 8]) = w;
    }

    // ---------- once per block: per-lane weight/bias fragments ----------
    half8 b_w2[2];
    #pragma unroll
    for (int ct = 0; ct < 2; ++ct)
        #pragma unroll
        for (int j = 0; j < 8; ++j)
            b_w2[ct][j] = (_Float16)W2[(q * 8 + j) * 32 + ct * 16 + ln];
    float b2v[2];
    b2v[0] = b2[ln]; b2v[1] = b2[16 + ln];
    float bm1v[4], wm2v[4];
    #pragma unroll
    for (int ct = 0; ct < 4; ++ct) {
        bm1v[ct] = bm1[ct * 16 + ln];
        wm2v[ct] = Wm2[ct * 16 + ln];
    }
    const float bm2s = bm2[0];

    __syncthreads();   // wm1t staged (the ONLY barrier in the kernel)

    const int NT = (rows + 63) >> 6;              // 64-row wave-tiles
    const int wid_g = blockIdx.x * 4 + (tid >> 6); // global wave id (3072)

    // ---------- steal/assign first tile + prologue prefetch ----------
    int t_cur = wid_g;
    if (use_steal) {
        int t0;
        if (lane == 0) t0 = atomicAdd(cursor, 1);
        t_cur = __shfl(t0, 0);
    }

    int ndr[4] = {0, 0, 0, 0};
    int kkc = 0;
    float4 enc = {0.f, 0.f, 0.f, 0.f};
    half8 fA01[2][2];
    if (t_cur < NT) {
        const int rb = t_cur << 6;
        #pragma unroll
        for (int rt = 0; rt < 4; ++rt)
            ndr[rt] = node_idx[rb + rt * 16 + ln];
        kkc = key_idx[rb + lane];
        enc = *(const float4*)(pos_table + (size_t)kkc * 4);
        load_feat2(feat16, node_feat, use_f16, ndr[0], ndr[1], q, fA01);
    }

    while (t_cur < NT) {
        const int rb = t_cur << 6;

        // ---- steal next tile (atomic latency hidden under this iter) ----
        int t_next;
        if (use_steal) {
            int tn;
            if (lane == 0) tn = atomicAdd(cursor, 1);
            t_next = __shfl(tn, 0);
        } else {
            t_next = t_cur + GRID_MAIN * 4;
        }
        const bool more = t_next < NT;

        // ---- iter top: only the rt{2,3} feat gathers (ndr resident) ----
        half8 fA23[2][2];
        load_feat2(feat16, node_feat, use_f16, ndr[2], ndr[3], q, fA23);

        // ---- next-tile independent index loads ----
        int ndr_n[4];
        int kk_n;
        if (more) {
            const int rbn = t_next << 6;
            #pragma unroll
            for (int rt = 0; rt < 4; ++rt)
                ndr_n[rt] = node_idx[rbn + rt * 16 + ln];
            kk_n = key_idx[rbn + lane];
        } else {
            #pragma unroll
            for (int rt = 0; rt < 4; ++rt)
                ndr_n[rt] = 0;
            kk_n = 0;
        }

        // ---- GEMM1 (VALU fp32, enc already resident) -> h ----
        #pragma unroll
        for (int g = 0; g < 4; ++g) {
            half8 hv;
            #pragma unroll
            for (int j8 = 0; j8 < 8; ++j8) {
                const int j = g * 8 + j8;
                float a = fmaf(enc.w, W1[96 + j],
                          fmaf(enc.z, W1[64 + j],
                          fmaf(enc.y, W1[32 + j],
                          fmaf(enc.x, W1[j], b1[j]))));
                hv[j8] = (_Float16)fmaxf(a, 0.0f);
            }
            *(half8*)(&hpe[tid * HSTR + g * 8]) = hv;
        }
        // wave-private transpose read — no barrier (same wave wrote it)
        half8 a_h[4];
        #pragma unroll
        for (int rt = 0; rt < 4; ++rt)
            a_h[rt] = *(const half8*)(&hpe[(r0 + rt * 16 + ln) * HSTR + q * 8]);

        // ---- GEMM2: 8 MFMA -> pe (C-layout regs) ----
        floatx4 pc[4][2];
        #pragma unroll
        for (int rt = 0; rt < 4; ++rt)
            #pragma unroll
            for (int ct = 0; ct < 2; ++ct) {
                floatx4 c = {0.f, 0.f, 0.f, 0.f};
                pc[rt][ct] = __builtin_amdgcn_mfma_f32_16x16x32_f16(
                    a_h[rt], b_w2[ct], c, 0, 0, 0);
            }

        // write pe into the SAME buffer (h consumed; own wave's slice only)
        #pragma unroll
        for (int rt = 0; rt < 4; ++rt)
            #pragma unroll
            for (int ct = 0; ct < 2; ++ct)
                #pragma unroll
                for (int r = 0; r < 4; ++r)
                    hpe[(r0 + rt * 16 + q * 4 + r) * HSTR + ct * 16 + ln] =
                        (_Float16)(pc[rt][ct][r] + b2v[ct]);
        // no barrier: reader below is the same wave

        // ---- next-tile enc gather (kk_n has had GEMM1+GEMM2 to land) ----
        float4 enc_n = enc;
        if (more)
            enc_n = *(const float4*)(pos_table + (size_t)kk_n * 4);

        // ---- GEMM3: 48 MFMA ----
        floatx4 acc[4][4];
        #pragma unroll
        for (int ct = 0; ct < 4; ++ct) {
            const float bb = bm1v[ct];
            #pragma unroll
            for (int rt = 0; rt < 4; ++rt)
                acc[rt][ct] = (floatx4){bb, bb, bb, bb};
        }

        {   // ktile 0: A = pe from LDS
            half8 a_pe[4];
            #pragma unroll
            for (int rt = 0; rt < 4; ++rt)
                a_pe[rt] = *(const half8*)(&hpe[(r0 + rt * 16 + ln) * HSTR + q * 8]);
            half8 b0[4];
            #pragma unroll
            for (int ct = 0; ct < 4; ++ct)
                b0[ct] = *(const half8*)(&wm1t[(ct * 16 + ln) * WSTR + q * 8]);
            #pragma unroll
            for (int rt = 0; rt < 4; ++rt)
                #pragma unroll
                for (int ct = 0; ct < 4; ++ct)
                    acc[rt][ct] = __builtin_amdgcn_mfma_f32_16x16x32_f16(
                        a_pe[rt], b0[ct], acc[rt][ct], 0, 0, 0);
        }

        #pragma unroll
        for (int kt = 0; kt < 2; ++kt) {   // ktiles 1,2: A = feat
            half8 bk[4];
            #pragma unroll
            for (int ct = 0; ct < 4; ++ct)
                bk[ct] = *(const half8*)(&wm1t[(ct * 16 + ln) * WSTR + 32 + kt * 32 + q * 8]);
            #pragma unroll
            for (int ct = 0; ct < 4; ++ct) {
                acc[0][ct] = __builtin_amdgcn_mfma_f32_16x16x32_f16(
                    fA01[0][kt], bk[ct], acc[0][ct], 0, 0, 0);
                acc[1][ct] = __builtin_amdgcn_mfma_f32_16x16x32_f16(
                    fA01[1][kt], bk[ct], acc[1][ct], 0, 0, 0);
                acc[2][ct] = __builtin_amdgcn_mfma_f32_16x16x32_f16(
                    fA23[0][kt], bk[ct], acc[2][ct], 0, 0, 0);
                acc[3][ct] = __builtin_amdgcn_mfma_f32_16x16x32_f16(
                    fA23[1][kt], bk[ct], acc[3][ct], 0, 0, 0);
            }
        }

        // ---- fA consumed: prefetch NEXT-tile fA01 (rt 0,1) now ----
        half8 fA01_n[2][2];
        load_feat2(feat16, node_feat, use_f16, ndr_n[0], ndr_n[1], q, fA01_n);

        // ---- GEMM4: relu + Wm2 dot + 4-step butterfly + store ----
        #pragma unroll
        for (int rt = 0; rt < 4; ++rt) {
            #pragma unroll
            for (int r = 0; r < 4; ++r) {
                float p = 0.0f;
                #pragma unroll
                for (int ct = 0; ct < 4; ++ct)
                    p = fmaf(fmaxf(acc[rt][ct][r], 0.0f), wm2v[ct], p);
                p += __shfl_xor(p, 1);
                p += __shfl_xor(p, 2);
                p += __shfl_xor(p, 4);
                p += __shfl_xor(p, 8);
                const int orow = rb + rt * 16 + q * 4 + r;
                if (ln == 0 && orow < rows)
                    out[orow] = p + bm2s;
            }
        }

        // ---- rotate pipeline state ----
        t_cur = t_next;
        #pragma unroll
        for (int rt = 0; rt < 4; ++rt)
            ndr[rt] = ndr_n[rt];
        kkc = kk_n;
        enc = enc_n;
        #pragma unroll
        for (int rr = 0; rr < 2; ++rr)
            #pragma unroll
            for (int kt = 0; kt < 2; ++kt)
                fA01[rr][kt] = fA01_n[rr][kt];
    }
}

extern "C" void kernel_launch(void* const* d_in, const int* in_sizes, int n_in,
                              void* d_out, int out_size, void* d_ws, size_t ws_size,
                              hipStream_t stream) {
    const float* pos_table = (const float*)d_in[0];
    const float* node_feat = (const float*)d_in[1];
    const float* W1        = (const float*)d_in[2];
    const float* b1        = (const float*)d_in[3];
    const float* W2        = (const float*)d_in[4];
    const float* b2        = (const float*)d_in[5];
    const float* Wm1       = (const float*)d_in[6];
    const float* bm1       = (const float*)d_in[7];
    const float* Wm2       = (const float*)d_in[8];
    const float* bm2       = (const float*)d_in[9];
    const int*   key_idx   = (const int*)d_in[10];
    const int*   node_idx  = (const int*)d_in[11];
    float* out = (float*)d_out;

    const int rows  = in_sizes[10];                // 1,048,576
    const int nfeat = in_sizes[1];                 // NUM_NODES*64

    // ws layout: [0,4)   tile cursor (zeroed each launch)
    //            [256,.) feat16 table
    int* cursor = (int*)d_ws;
    const int use_steal = (ws_size >= 4) ? 1 : 0;

    _Float16* feat16 = (_Float16*)((char*)d_ws + 256);
    const size_t need = 256 + (size_t)nfeat * sizeof(_Float16);
    const int use_f16 = (ws_size >= need) ? 1 : 0;

    if (use_steal)
        hipMemsetAsync(cursor, 0, 4, stream);
    if (use_f16) {
        const int n8 = nfeat / 8;
        feat_to_f16<<<(n8 + 255) / 256, 256, 0, stream>>>(node_feat, feat16, n8);
    }

    neurtw_r18<<<GRID_MAIN, 256, 0, stream>>>(
        pos_table, node_feat, W1, b1, W2, b2, Wm1, bm1, Wm2, bm2,
        key_idx, node_idx, feat16, use_f16, cursor, use_steal, out, rows);
}

// Round 10
// 172.749 us; speedup vs baseline: 1.9700x; 1.9700x over previous
//
#include <hip/hip_runtime.h>

// NeurTWs R19b = R19 resubmitted verbatim (previous round's bench died on
// "MI355X container failed twice" -- infra error, no kernel evidence).
// R19 = R17 (best: 55.7us steady, 84 VGPR, no spill) + two safe levers.
// R18 post-mortem: single-cursor work-stealing collapsed to 238us
// -- 3072 waves queue on one device-scope line, per-wave atomic LATENCY
// (queue depth x service ~ tens of us) lands on the shfl->ndr dependency
// chain every iteration. Stealing reverted; the 12.5% tail quantization
// (per-CU 16 block-iters / 3 slots -> ceil 6 vs 5.33) is only buyable
// via smaller tiles, kept in pocket. R19 levers on R17:
//  (1) FULL-deep feat prefetch: fA23 also cross-iteration (R17 only did
//      fA01, gained 3.5us; fA23's iter-top load had ~1500cy cover --
//      enough on average, jitter-exposed at 3 waves). GEMM3 feat ktiles
//      split rt01-then-rt23 so each pair is consumed before its
//      replacement issues (+8 ds_read_b128/iter ~ 100cy, noise).
//  (2) Coalesced output store: old epilogue = 16 exec-masked scalar
//      stores (4 lanes x 4B at stride 16B = partial-line writes; WRITE
//      11MB vs 4MB output = ~7MB RMW overhead). New: stage 64 f32 in the
//      wave's own consumed hpe slice, then ONE 256B coalesced
//      global_store_dword per wave. Wave-private DS, no barrier.
// Decisive counters: WRITE ~4-6MB (coalescing works), VGPR<=106 no
// spill. Pre-commit: >=55us => declare micro-levers done; last option is
// 32-row tiles (tail 12.5->3%) or roofline.
// Fragment layouts (gfx950, verified): A/B: idx=lane&15, k=(lane>>4)*8+j;
// C/D: col=lane&15, row=(lane>>4)*4+reg.

typedef _Float16 half8 __attribute__((ext_vector_type(8)));
typedef float floatx4 __attribute__((ext_vector_type(4)));

#define HSTR 40    // h/pe row stride (f16): 80 B
#define WSTR 104   // wm1t row stride (f16): 208 B
#define GRID_MAIN 768

__global__ void feat_to_f16(const float* __restrict__ nf,
                            _Float16* __restrict__ o, int n8) {
    int t = blockIdx.x * 256 + threadIdx.x;
    if (t >= n8) return;
    const float4* p = (const float4*)nf + (size_t)t * 2;
    const float4 a = p[0], b = p[1];
    half8 h;
    h[0] = (_Float16)a.x; h[1] = (_Float16)a.y;
    h[2] = (_Float16)a.z; h[3] = (_Float16)a.w;
    h[4] = (_Float16)b.x; h[5] = (_Float16)b.y;
    h[6] = (_Float16)b.z; h[7] = (_Float16)b.w;
    *((half8*)o + t) = h;
}

// load feat A-fragments for 2 row-tiles (nd0 -> fA[0], nd1 -> fA[1])
__device__ __forceinline__ void load_feat2(const _Float16* __restrict__ feat16,
                                           const float* __restrict__ node_feat,
                                           int use_f16, int nd0, int nd1, int q,
                                           half8 fA[2][2]) {
    if (use_f16) {
        const _Float16* fb0 = feat16 + (size_t)nd0 * 64 + q * 8;
        const _Float16* fb1 = feat16 + (size_t)nd1 * 64 + q * 8;
        fA[0][0] = *(const half8*)(fb0);
        fA[0][1] = *(const half8*)(fb0 + 32);
        fA[1][0] = *(const half8*)(fb1);
        fA[1][1] = *(const half8*)(fb1 + 32);
    } else {
        #pragma unroll
        for (int rr = 0; rr < 2; ++rr) {
            const float* fb = node_feat + (size_t)(rr ? nd1 : nd0) * 64 + q * 8;
            #pragma unroll
            for (int kt = 0; kt < 2; ++kt) {
                const float4 lo = *(const float4*)(fb + kt * 32);
                const float4 hi = *(const float4*)(fb + kt * 32 + 4);
                half8 h;
                h[0] = (_Float16)lo.x; h[1] = (_Float16)lo.y;
                h[2] = (_Float16)lo.z; h[3] = (_Float16)lo.w;
                h[4] = (_Float16)hi.x; h[5] = (_Float16)hi.y;
                h[6] = (_Float16)hi.z; h[7] = (_Float16)hi.w;
                fA[rr][kt] = h;
            }
        }
    }
}

__global__ __launch_bounds__(256, 3) void neurtw_r19(
    const float* __restrict__ pos_table,   // [NUM_KEYS, 4]
    const float* __restrict__ node_feat,   // [NUM_NODES, 64] fp32 (fallback)
    const float* __restrict__ W1,          // [4, 32]
    const float* __restrict__ b1,          // [32]
    const float* __restrict__ W2,          // [32, 32]
    const float* __restrict__ b2,          // [32]
    const float* __restrict__ Wm1,         // [96, 64]
    const float* __restrict__ bm1,         // [64]
    const float* __restrict__ Wm2,         // [64, 1]
    const float* __restrict__ bm2,         // [1]
    const int*   __restrict__ key_idx,     // [rows]
    const int*   __restrict__ node_idx,    // [rows]
    const _Float16* __restrict__ feat16,   // [NUM_NODES, 64] f16 (ws)
    int use_f16,
    float*       __restrict__ out,         // [rows]
    int rows)
{
    __shared__ _Float16 hpe[256 * HSTR];   // 20 KB (h then pe; wave-private)
    __shared__ _Float16 wm1t[64 * WSTR];   // 13 KB  wm1t[n][k] = Wm1[k][n]

    const int tid  = threadIdx.x;
    const int lane = tid & 63;
    const int r0   = (tid >> 6) * 64;
    const int ln   = lane & 15;
    const int q    = lane >> 4;

    // ---------- once per block: stage Wm1^T into LDS ----------
    #pragma unroll
    for (int i = 0; i < 3; ++i) {
        const int task = i * 256 + tid;
        const int n = task & 63, k8 = task >> 6;
        half8 w;
        #pragma unroll
        for (int kk = 0; kk < 8; ++kk)
            w[kk] = (_Float16)Wm1[(k8 * 8 + kk) * 64 + n];
        *(half8*)(&wm1t[n * WSTR + k8 * 8]) = w;
    }

    // ---------- once per block: per-lane weight/bias fragments ----------
    half8 b_w2[2];
    #pragma unroll
    for (int ct = 0; ct < 2; ++ct)
        #pragma unroll
        for (int j = 0; j < 8; ++j)
            b_w2[ct][j] = (_Float16)W2[(q * 8 + j) * 32 + ct * 16 + ln];
    float b2v[2];
    b2v[0] = b2[ln]; b2v[1] = b2[16 + ln];
    float bm1v[4], wm2v[4];
    #pragma unroll
    for (int ct = 0; ct < 4; ++ct) {
        bm1v[ct] = bm1[ct * 16 + ln];
        wm2v[ct] = Wm2[ct * 16 + ln];
    }
    const float bm2s = bm2[0];

    __syncthreads();   // wm1t staged (the ONLY barrier in the kernel)

    // ---------- pipeline prologue: iter-0 indices + enc + ALL feat ----------
    int base = blockIdx.x * 256;
    int ndr[4];
    #pragma unroll
    for (int rt = 0; rt < 4; ++rt)
        ndr[rt] = node_idx[base + r0 + rt * 16 + ln];
    int kkc = key_idx[base + tid];
    float4 enc = *(const float4*)(pos_table + (size_t)kkc * 4);
    half8 fA01[2][2], fA23[2][2];
    load_feat2(feat16, node_feat, use_f16, ndr[0], ndr[1], q, fA01);
    load_feat2(feat16, node_feat, use_f16, ndr[2], ndr[3], q, fA23);

    while (base < rows) {
        const int nbase = base + GRID_MAIN * 256;
        const bool more = nbase < rows;

        // ---- next-iter independent index loads ----
        int ndr_n[4];
        int kk_n;
        if (more) {
            #pragma unroll
            for (int rt = 0; rt < 4; ++rt)
                ndr_n[rt] = node_idx[nbase + r0 + rt * 16 + ln];
            kk_n = key_idx[nbase + tid];
        } else {
            #pragma unroll
            for (int rt = 0; rt < 4; ++rt)
                ndr_n[rt] = 0;
            kk_n = 0;
        }

        // ---- GEMM1 (VALU fp32, enc already resident) -> h ----
        #pragma unroll
        for (int g = 0; g < 4; ++g) {
            half8 hv;
            #pragma unroll
            for (int j8 = 0; j8 < 8; ++j8) {
                const int j = g * 8 + j8;
                float a = fmaf(enc.w, W1[96 + j],
                          fmaf(enc.z, W1[64 + j],
                          fmaf(enc.y, W1[32 + j],
                          fmaf(enc.x, W1[j], b1[j]))));
                hv[j8] = (_Float16)fmaxf(a, 0.0f);
            }
            *(half8*)(&hpe[tid * HSTR + g * 8]) = hv;
        }
        // wave-private transpose read — no barrier (same wave wrote it)
        half8 a_h[4];
        #pragma unroll
        for (int rt = 0; rt < 4; ++rt)
            a_h[rt] = *(const half8*)(&hpe[(r0 + rt * 16 + ln) * HSTR + q * 8]);

        // ---- GEMM2: 8 MFMA -> pe (C-layout regs) ----
        floatx4 pc[4][2];
        #pragma unroll
        for (int rt = 0; rt < 4; ++rt)
            #pragma unroll
            for (int ct = 0; ct < 2; ++ct) {
                floatx4 c = {0.f, 0.f, 0.f, 0.f};
                pc[rt][ct] = __builtin_amdgcn_mfma_f32_16x16x32_f16(
                    a_h[rt], b_w2[ct], c, 0, 0, 0);
            }

        // write pe into the SAME buffer (h consumed; own wave's slice only)
        #pragma unroll
        for (int rt = 0; rt < 4; ++rt)
            #pragma unroll
            for (int ct = 0; ct < 2; ++ct)
                #pragma unroll
                for (int r = 0; r < 4; ++r)
                    hpe[(r0 + rt * 16 + q * 4 + r) * HSTR + ct * 16 + ln] =
                        (_Float16)(pc[rt][ct][r] + b2v[ct]);
        // no barrier: reader below is the same wave

        // ---- next-iter enc gather (kk_n has had GEMM1+GEMM2 to land) ----
        float4 enc_n = enc;
        if (more)
            enc_n = *(const float4*)(pos_table + (size_t)kk_n * 4);

        // ---- GEMM3: 48 MFMA ----
        floatx4 acc[4][4];
        #pragma unroll
        for (int ct = 0; ct < 4; ++ct) {
            const float bb = bm1v[ct];
            #pragma unroll
            for (int rt = 0; rt < 4; ++rt)
                acc[rt][ct] = (floatx4){bb, bb, bb, bb};
        }

        {   // ktile 0: A = pe from LDS
            half8 a_pe[4];
            #pragma unroll
            for (int rt = 0; rt < 4; ++rt)
                a_pe[rt] = *(const half8*)(&hpe[(r0 + rt * 16 + ln) * HSTR + q * 8]);
            half8 b0[4];
            #pragma unroll
            for (int ct = 0; ct < 4; ++ct)
                b0[ct] = *(const half8*)(&wm1t[(ct * 16 + ln) * WSTR + q * 8]);
            #pragma unroll
            for (int rt = 0; rt < 4; ++rt)
                #pragma unroll
                for (int ct = 0; ct < 4; ++ct)
                    acc[rt][ct] = __builtin_amdgcn_mfma_f32_16x16x32_f16(
                        a_pe[rt], b0[ct], acc[rt][ct], 0, 0, 0);
        }

        // feat ktiles for rt 0,1 (consume fA01 fully)
        #pragma unroll
        for (int kt = 0; kt < 2; ++kt) {
            half8 bk[4];
            #pragma unroll
            for (int ct = 0; ct < 4; ++ct)
                bk[ct] = *(const half8*)(&wm1t[(ct * 16 + ln) * WSTR + 32 + kt * 32 + q * 8]);
            #pragma unroll
            for (int rr = 0; rr < 2; ++rr)
                #pragma unroll
                for (int ct = 0; ct < 4; ++ct)
                    acc[rr][ct] = __builtin_amdgcn_mfma_f32_16x16x32_f16(
                        fA01[rr][kt], bk[ct], acc[rr][ct], 0, 0, 0);
        }
        // fA01 consumed -> prefetch next-iter fA01
        load_feat2(feat16, node_feat, use_f16, ndr_n[0], ndr_n[1], q, fA01);

        // feat ktiles for rt 2,3 (consume fA23 fully)
        #pragma unroll
        for (int kt = 0; kt < 2; ++kt) {
            half8 bk[4];
            #pragma unroll
            for (int ct = 0; ct < 4; ++ct)
                bk[ct] = *(const half8*)(&wm1t[(ct * 16 + ln) * WSTR + 32 + kt * 32 + q * 8]);
            #pragma unroll
            for (int rr = 0; rr < 2; ++rr)
                #pragma unroll
                for (int ct = 0; ct < 4; ++ct)
                    acc[2 + rr][ct] = __builtin_amdgcn_mfma_f32_16x16x32_f16(
                        fA23[rr][kt], bk[ct], acc[2 + rr][ct], 0, 0, 0);
        }
        // fA23 consumed -> prefetch next-iter fA23
        load_feat2(feat16, node_feat, use_f16, ndr_n[2], ndr_n[3], q, fA23);

        // ---- GEMM4: relu + Wm2 dot + butterfly; stage in LDS; coalesced ----
        // hpe wave slice is fully consumed (pe read in ktile0) -> reuse as
        // a 64-float staging buffer for this wave's outputs.
        float* s_out = (float*)&hpe[r0 * HSTR];
        #pragma unroll
        for (int rt = 0; rt < 4; ++rt) {
            #pragma unroll
            for (int r = 0; r < 4; ++r) {
                float p = 0.0f;
                #pragma unroll
                for (int ct = 0; ct < 4; ++ct)
                    p = fmaf(fmaxf(acc[rt][ct][r], 0.0f), wm2v[ct], p);
                p += __shfl_xor(p, 1);
                p += __shfl_xor(p, 2);
                p += __shfl_xor(p, 4);
                p += __shfl_xor(p, 8);
                if (ln == 0)
                    s_out[rt * 16 + q * 4 + r] = p + bm2s;
            }
        }
        // same-wave DS in-order: one coalesced 256B store per wave
        out[base + r0 + lane] = s_out[lane];

        // ---- rotate pipeline state ----
        base = nbase;
        #pragma unroll
        for (int rt = 0; rt < 4; ++rt)
            ndr[rt] = ndr_n[rt];
        kkc = kk_n;
        enc = enc_n;
    }
}

extern "C" void kernel_launch(void* const* d_in, const int* in_sizes, int n_in,
                              void* d_out, int out_size, void* d_ws, size_t ws_size,
                              hipStream_t stream) {
    const float* pos_table = (const float*)d_in[0];
    const float* node_feat = (const float*)d_in[1];
    const float* W1        = (const float*)d_in[2];
    const float* b1        = (const float*)d_in[3];
    const float* W2        = (const float*)d_in[4];
    const float* b2        = (const float*)d_in[5];
    const float* Wm1       = (const float*)d_in[6];
    const float* bm1       = (const float*)d_in[7];
    const float* Wm2       = (const float*)d_in[8];
    const float* bm2       = (const float*)d_in[9];
    const int*   key_idx   = (const int*)d_in[10];
    const int*   node_idx  = (const int*)d_in[11];
    float* out = (float*)d_out;

    const int rows  = in_sizes[10];                // 1,048,576
    const int nfeat = in_sizes[1];                 // NUM_NODES*64

    _Float16* feat16 = (_Float16*)d_ws;
    const size_t need = (size_t)nfeat * sizeof(_Float16);
    const int use_f16 = (ws_size >= need) ? 1 : 0;

    if (use_f16) {
        const int n8 = nfeat / 8;
        feat_to_f16<<<(n8 + 255) / 256, 256, 0, stream>>>(node_feat, feat16, n8);
    }

    neurtw_r19<<<GRID_MAIN, 256, 0, stream>>>(
        pos_table, node_feat, W1, b1, W2, b2, Wm1, bm1, Wm2, bm2,
        key_idx, node_idx, feat16, use_f16, out, rows);
}

// Round 11
// 151.617 us; speedup vs baseline: 2.2445x; 1.1394x over previous
//
#include <hip/hip_runtime.h>

// NeurTWs R20 = R17 body EXACTLY (proven 55.7us, 84 VGPR, no spill) +
// coalesced output store ONLY. R19 post-mortem: the fA23 full-deep
// prefetch (32 loop-carried VGPRs vs R17's 16) re-triggered the spill
// (WRITE 34MB = 30MB scratch, FETCH +66MB reloads, 77.5us) -- 4th
// confirmation that extending cross-iter register state past R17's
// footprint spills. fA23 deep prefetch is DEAD; fA23 reverts to its
// R17 iter-top slot (~1500cy cover). The untested lever rides alone:
//  - Epilogue: old = 16 exec-masked scalar stores/thread (4 lanes x 4B
//    @ stride 16B = partial-line RMW; R17 WRITE 11MB vs 4MB output).
//    New = butterfly as before, ln==0 lanes write their 16 results into
//    the wave's own CONSUMED hpe slice (pe was read in ktile0; same-wave
//    DS is in-order, validated pattern since R5/R6), then ONE coalesced
//    256B store per wave: out[base+r0+lane] = s_out[lane].
// Decisive counters: WRITE 11 -> ~4.5-6MB, VGPR ~84 (WRITE<=6MB is the
// no-spill proof), FETCH ~131MB. Pre-commit: >=55.5us with WRITE ~5MB
// => writes weren't on the critical path; kernel is at its 3-wave
// latency/issue equilibrium (4-wave spills x4, steal-atomics dead,
// pos16 null, deeper prefetch spills) => declare roofline.
// Fragment layouts (gfx950, verified): A/B: idx=lane&15, k=(lane>>4)*8+j;
// C/D: col=lane&15, row=(lane>>4)*4+reg.

typedef _Float16 half8 __attribute__((ext_vector_type(8)));
typedef float floatx4 __attribute__((ext_vector_type(4)));

#define HSTR 40    // h/pe row stride (f16): 80 B
#define WSTR 104   // wm1t row stride (f16): 208 B
#define GRID_MAIN 768

__global__ void feat_to_f16(const float* __restrict__ nf,
                            _Float16* __restrict__ o, int n8) {
    int t = blockIdx.x * 256 + threadIdx.x;
    if (t >= n8) return;
    const float4* p = (const float4*)nf + (size_t)t * 2;
    const float4 a = p[0], b = p[1];
    half8 h;
    h[0] = (_Float16)a.x; h[1] = (_Float16)a.y;
    h[2] = (_Float16)a.z; h[3] = (_Float16)a.w;
    h[4] = (_Float16)b.x; h[5] = (_Float16)b.y;
    h[6] = (_Float16)b.z; h[7] = (_Float16)b.w;
    *((half8*)o + t) = h;
}

// load feat A-fragments for 2 row-tiles (nd0 -> fA[0], nd1 -> fA[1])
__device__ __forceinline__ void load_feat2(const _Float16* __restrict__ feat16,
                                           const float* __restrict__ node_feat,
                                           int use_f16, int nd0, int nd1, int q,
                                           half8 fA[2][2]) {
    if (use_f16) {
        const _Float16* fb0 = feat16 + (size_t)nd0 * 64 + q * 8;
        const _Float16* fb1 = feat16 + (size_t)nd1 * 64 + q * 8;
        fA[0][0] = *(const half8*)(fb0);
        fA[0][1] = *(const half8*)(fb0 + 32);
        fA[1][0] = *(const half8*)(fb1);
        fA[1][1] = *(const half8*)(fb1 + 32);
    } else {
        #pragma unroll
        for (int rr = 0; rr < 2; ++rr) {
            const float* fb = node_feat + (size_t)(rr ? nd1 : nd0) * 64 + q * 8;
            #pragma unroll
            for (int kt = 0; kt < 2; ++kt) {
                const float4 lo = *(const float4*)(fb + kt * 32);
                const float4 hi = *(const float4*)(fb + kt * 32 + 4);
                half8 h;
                h[0] = (_Float16)lo.x; h[1] = (_Float16)lo.y;
                h[2] = (_Float16)lo.z; h[3] = (_Float16)lo.w;
                h[4] = (_Float16)hi.x; h[5] = (_Float16)hi.y;
                h[6] = (_Float16)hi.z; h[7] = (_Float16)hi.w;
                fA[rr][kt] = h;
            }
        }
    }
}

__global__ __launch_bounds__(256, 3) void neurtw_r20(
    const float* __restrict__ pos_table,   // [NUM_KEYS, 4]
    const float* __restrict__ node_feat,   // [NUM_NODES, 64] fp32 (fallback)
    const float* __restrict__ W1,          // [4, 32]
    const float* __restrict__ b1,          // [32]
    const float* __restrict__ W2,          // [32, 32]
    const float* __restrict__ b2,          // [32]
    const float* __restrict__ Wm1,         // [96, 64]
    const float* __restrict__ bm1,         // [64]
    const float* __restrict__ Wm2,         // [64, 1]
    const float* __restrict__ bm2,         // [1]
    const int*   __restrict__ key_idx,     // [rows]
    const int*   __restrict__ node_idx,    // [rows]
    const _Float16* __restrict__ feat16,   // [NUM_NODES, 64] f16 (ws)
    int use_f16,
    float*       __restrict__ out,         // [rows]
    int rows)
{
    __shared__ _Float16 hpe[256 * HSTR];   // 20 KB (h then pe; wave-private)
    __shared__ _Float16 wm1t[64 * WSTR];   // 13 KB  wm1t[n][k] = Wm1[k][n]

    const int tid  = threadIdx.x;
    const int lane = tid & 63;
    const int r0   = (tid >> 6) * 64;
    const int ln   = lane & 15;
    const int q    = lane >> 4;

    // ---------- once per block: stage Wm1^T into LDS ----------
    #pragma unroll
    for (int i = 0; i < 3; ++i) {
        const int task = i * 256 + tid;
        const int n = task & 63, k8 = task >> 6;
        half8 w;
        #pragma unroll
        for (int kk = 0; kk < 8; ++kk)
            w[kk] = (_Float16)Wm1[(k8 * 8 + kk) * 64 + n];
        *(half8*)(&wm1t[n * WSTR + k8 * 8]) = w;
    }

    // ---------- once per block: per-lane weight/bias fragments ----------
    half8 b_w2[2];
    #pragma unroll
    for (int ct = 0; ct < 2; ++ct)
        #pragma unroll
        for (int j = 0; j < 8; ++j)
            b_w2[ct][j] = (_Float16)W2[(q * 8 + j) * 32 + ct * 16 + ln];
    float b2v[2];
    b2v[0] = b2[ln]; b2v[1] = b2[16 + ln];
    float bm1v[4], wm2v[4];
    #pragma unroll
    for (int ct = 0; ct < 4; ++ct) {
        bm1v[ct] = bm1[ct * 16 + ln];
        wm2v[ct] = Wm2[ct * 16 + ln];
    }
    const float bm2s = bm2[0];

    __syncthreads();   // wm1t staged (the ONLY barrier in the kernel)

    // ---------- pipeline prologue: iter-0 indices + enc + fA01 ----------
    int base = blockIdx.x * 256;
    int ndr[4];
    #pragma unroll
    for (int rt = 0; rt < 4; ++rt)
        ndr[rt] = node_idx[base + r0 + rt * 16 + ln];
    int kkc = key_idx[base + tid];
    float4 enc = *(const float4*)(pos_table + (size_t)kkc * 4);
    half8 fA01[2][2];
    load_feat2(feat16, node_feat, use_f16, ndr[0], ndr[1], q, fA01);

    while (base < rows) {
        const int nbase = base + GRID_MAIN * 256;
        const bool more = nbase < rows;

        // ---- iter top: only the rt{2,3} feat gathers (ndr resident) ----
        half8 fA23[2][2];
        load_feat2(feat16, node_feat, use_f16, ndr[2], ndr[3], q, fA23);

        // ---- next-iter independent index loads ----
        int ndr_n[4];
        int kk_n;
        if (more) {
            #pragma unroll
            for (int rt = 0; rt < 4; ++rt)
                ndr_n[rt] = node_idx[nbase + r0 + rt * 16 + ln];
            kk_n = key_idx[nbase + tid];
        } else {
            #pragma unroll
            for (int rt = 0; rt < 4; ++rt)
                ndr_n[rt] = 0;
            kk_n = 0;
        }

        // ---- GEMM1 (VALU fp32, enc already resident) -> h ----
        #pragma unroll
        for (int g = 0; g < 4; ++g) {
            half8 hv;
            #pragma unroll
            for (int j8 = 0; j8 < 8; ++j8) {
                const int j = g * 8 + j8;
                float a = fmaf(enc.w, W1[96 + j],
                          fmaf(enc.z, W1[64 + j],
                          fmaf(enc.y, W1[32 + j],
                          fmaf(enc.x, W1[j], b1[j]))));
                hv[j8] = (_Float16)fmaxf(a, 0.0f);
            }
            *(half8*)(&hpe[tid * HSTR + g * 8]) = hv;
        }
        // wave-private transpose read — no barrier (same wave wrote it)
        half8 a_h[4];
        #pragma unroll
        for (int rt = 0; rt < 4; ++rt)
            a_h[rt] = *(const half8*)(&hpe[(r0 + rt * 16 + ln) * HSTR + q * 8]);

        // ---- GEMM2: 8 MFMA -> pe (C-layout regs) ----
        floatx4 pc[4][2];
        #pragma unroll
        for (int rt = 0; rt < 4; ++rt)
            #pragma unroll
            for (int ct = 0; ct < 2; ++ct) {
                floatx4 c = {0.f, 0.f, 0.f, 0.f};
                pc[rt][ct] = __builtin_amdgcn_mfma_f32_16x16x32_f16(
                    a_h[rt], b_w2[ct], c, 0, 0, 0);
            }

        // write pe into the SAME buffer (h consumed; own wave's slice only)
        #pragma unroll
        for (int rt = 0; rt < 4; ++rt)
            #pragma unroll
            for (int ct = 0; ct < 2; ++ct)
                #pragma unroll
                for (int r = 0; r < 4; ++r)
                    hpe[(r0 + rt * 16 + q * 4 + r) * HSTR + ct * 16 + ln] =
                        (_Float16)(pc[rt][ct][r] + b2v[ct]);
        // no barrier: reader below is the same wave

        // ---- next-iter enc gather (kk_n has had GEMM1+GEMM2 to land) ----
        float4 enc_n = enc;
        if (more)
            enc_n = *(const float4*)(pos_table + (size_t)kk_n * 4);

        // ---- GEMM3: 48 MFMA ----
        floatx4 acc[4][4];
        #pragma unroll
        for (int ct = 0; ct < 4; ++ct) {
            const float bb = bm1v[ct];
            #pragma unroll
            for (int rt = 0; rt < 4; ++rt)
                acc[rt][ct] = (floatx4){bb, bb, bb, bb};
        }

        {   // ktile 0: A = pe from LDS
            half8 a_pe[4];
            #pragma unroll
            for (int rt = 0; rt < 4; ++rt)
                a_pe[rt] = *(const half8*)(&hpe[(r0 + rt * 16 + ln) * HSTR + q * 8]);
            half8 b0[4];
            #pragma unroll
            for (int ct = 0; ct < 4; ++ct)
                b0[ct] = *(const half8*)(&wm1t[(ct * 16 + ln) * WSTR + q * 8]);
            #pragma unroll
            for (int rt = 0; rt < 4; ++rt)
                #pragma unroll
                for (int ct = 0; ct < 4; ++ct)
                    acc[rt][ct] = __builtin_amdgcn_mfma_f32_16x16x32_f16(
                        a_pe[rt], b0[ct], acc[rt][ct], 0, 0, 0);
        }

        #pragma unroll
        for (int kt = 0; kt < 2; ++kt) {   // ktiles 1,2: A = feat
            half8 bk[4];
            #pragma unroll
            for (int ct = 0; ct < 4; ++ct)
                bk[ct] = *(const half8*)(&wm1t[(ct * 16 + ln) * WSTR + 32 + kt * 32 + q * 8]);
            #pragma unroll
            for (int ct = 0; ct < 4; ++ct) {
                acc[0][ct] = __builtin_amdgcn_mfma_f32_16x16x32_f16(
                    fA01[0][kt], bk[ct], acc[0][ct], 0, 0, 0);
                acc[1][ct] = __builtin_amdgcn_mfma_f32_16x16x32_f16(
                    fA01[1][kt], bk[ct], acc[1][ct], 0, 0, 0);
                acc[2][ct] = __builtin_amdgcn_mfma_f32_16x16x32_f16(
                    fA23[0][kt], bk[ct], acc[2][ct], 0, 0, 0);
                acc[3][ct] = __builtin_amdgcn_mfma_f32_16x16x32_f16(
                    fA23[1][kt], bk[ct], acc[3][ct], 0, 0, 0);
            }
        }

        // ---- fA consumed: prefetch NEXT-iter fA01 (rt 0,1) now ----
        // ndr_n arrived ~1500cy ago; cover = GEMM4 + next GEMM1/2 ~1800cy.
        half8 fA01_n[2][2];
        load_feat2(feat16, node_feat, use_f16, ndr_n[0], ndr_n[1], q, fA01_n);

        // ---- GEMM4: relu + Wm2 dot + butterfly; stage in LDS; coalesced ----
        // hpe wave slice fully consumed (pe read in ktile0) -> reuse as a
        // 64-float staging buffer; same-wave DS in-order, no barrier.
        float* s_out = (float*)&hpe[r0 * HSTR];
        #pragma unroll
        for (int rt = 0; rt < 4; ++rt) {
            #pragma unroll
            for (int r = 0; r < 4; ++r) {
                float p = 0.0f;
                #pragma unroll
                for (int ct = 0; ct < 4; ++ct)
                    p = fmaf(fmaxf(acc[rt][ct][r], 0.0f), wm2v[ct], p);
                p += __shfl_xor(p, 1);
                p += __shfl_xor(p, 2);
                p += __shfl_xor(p, 4);
                p += __shfl_xor(p, 8);
                if (ln == 0)
                    s_out[rt * 16 + q * 4 + r] = p + bm2s;
            }
        }
        // one coalesced 256B store per wave
        out[base + r0 + lane] = s_out[lane];

        // ---- rotate pipeline state ----
        base = nbase;
        #pragma unroll
        for (int rt = 0; rt < 4; ++rt)
            ndr[rt] = ndr_n[rt];
        kkc = kk_n;
        enc = enc_n;
        #pragma unroll
        for (int rr = 0; rr < 2; ++rr)
            #pragma unroll
            for (int kt = 0; kt < 2; ++kt)
                fA01[rr][kt] = fA01_n[rr][kt];
    }
}

extern "C" void kernel_launch(void* const* d_in, const int* in_sizes, int n_in,
                              void* d_out, int out_size, void* d_ws, size_t ws_size,
                              hipStream_t stream) {
    const float* pos_table = (const float*)d_in[0];
    const float* node_feat = (const float*)d_in[1];
    const float* W1        = (const float*)d_in[2];
    const float* b1        = (const float*)d_in[3];
    const float* W2        = (const float*)d_in[4];
    const float* b2        = (const float*)d_in[5];
    const float* Wm1       = (const float*)d_in[6];
    const float* bm1       = (const float*)d_in[7];
    const float* Wm2       = (const float*)d_in[8];
    const float* bm2       = (const float*)d_in[9];
    const int*   key_idx   = (const int*)d_in[10];
    const int*   node_idx  = (const int*)d_in[11];
    float* out = (float*)d_out;

    const int rows  = in_sizes[10];                // 1,048,576
    const int nfeat = in_sizes[1];                 // NUM_NODES*64

    _Float16* feat16 = (_Float16*)d_ws;
    const size_t need = (size_t)nfeat * sizeof(_Float16);
    const int use_f16 = (ws_size >= need) ? 1 : 0;

    if (use_f16) {
        const int n8 = nfeat / 8;
        feat_to_f16<<<(n8 + 255) / 256, 256, 0, stream>>>(node_feat, feat16, n8);
    }

    neurtw_r20<<<GRID_MAIN, 256, 0, stream>>>(
        pos_table, node_feat, W1, b1, W2, b2, Wm1, bm1, Wm2, bm2,
        key_idx, node_idx, feat16, use_f16, out, rows);
}